// Round 14
// baseline (186.750 us; speedup 1.0000x reference)
//
#include <hip/hip_runtime.h>

// AttentionMatcher R18: BJ=64 (32 tiles) — amortize per-tile fixed latency.
// R8-R17 lesson: every intra-tile micro-opt was neutral; attn time tracks
// (tiles x fixed-latency). R18 halves tile count, doubling work per barrier
// pair (64 barriers total, same as R12). Wave roles keep operand traffic
// optimal (R13/R15 law): QK wave (jt,kh) = j-half x K-half (Bc[2][4]);
// PV wave dq consumes 2 MtG 32-tiles/iter (Mtf[2][4]). SS 2 planes
// [64][68]f32 single-buf; PH [64][144B]; 2-barrier hazard structure = R7.
// In-place prefetch (no shadow regs): Bc reloaded after last QK use, Mtf
// at iter top. Keeps R17's register-(m,l) + exp2 domain.
// out = gate * softmax(N M^T, diag<-0) M + (1-gate) * N,  n=8192, d=256, fp32.
//
// ws: MhG [n][256] fp16 row-major          (QK B-plane)
//     MtG [n/32 tiles][256 d][32 j] fp16   (PV B-plane, transposed tile-major)
//     Ofp 3 fp16 partial O planes (splits 1..3); split-0 partial f32 in d_out
//     MLm/MLl [4][n] f32 running max (log2 domain) / sum per split.

constexpr int EMBED = 256;
constexpr int BQ = 64;
constexpr int BJ = 64;
constexpr int NT = 256;

constexpr int SS_OFF = 0;            // 2 planes x [64][68] f32 = 2 x 17408
constexpr int SS_PLW = 4352;         // plane stride in words
constexpr int PH_OFF = 34816;        // [64 q][144 B]
constexpr int AS_OFF = 44032;        // [64] f32
constexpr int LDS_SZ = 44288;        // x2 blocks/CU = 88.6 KB (<160)

typedef _Float16 half8 __attribute__((ext_vector_type(8)));
typedef float f32x4 __attribute__((ext_vector_type(4)));
typedef short short8v __attribute__((ext_vector_type(8)));

static __device__ __forceinline__ f32x4 mfma16(half8 a, half8 b, f32x4 c) {
    return __builtin_amdgcn_mfma_f32_16x16x32_f16(a, b, c, 0, 0, 0);
}
static __device__ __forceinline__ short f2h(float x) {
    return (short)__builtin_bit_cast(unsigned short, (_Float16)x);
}

// ---------- prep: fp16 row plane + fp16 transposed tile plane ----------
__global__ void prep(const float* __restrict__ M,
                     short* __restrict__ MhG, short* __restrict__ MtG) {
    __shared__ float L[16 * 260];
    const int r0 = blockIdx.x * 16;            // 16 M-rows per block
    const int t = threadIdx.x;
    const int pj = t >> 4, pc = (t & 15) * 16;
    {
        const float* src = M + (size_t)(r0 + pj) * EMBED + pc;
        float4 v[4];
        #pragma unroll
        for (int i = 0; i < 4; ++i) v[i] = ((const float4*)src)[i];
        short* hd = MhG + (size_t)(r0 + pj) * EMBED + pc;
        #pragma unroll
        for (int i = 0; i < 2; ++i) {
            float4 a = v[2 * i], b = v[2 * i + 1];
            short8v h;
            h[0]=f2h(a.x); h[1]=f2h(a.y); h[2]=f2h(a.z); h[3]=f2h(a.w);
            h[4]=f2h(b.x); h[5]=f2h(b.y); h[6]=f2h(b.z); h[7]=f2h(b.w);
            *(short8v*)(hd + 8 * i) = h;
        }
        #pragma unroll
        for (int i = 0; i < 4; ++i)
            *(float4*)(L + pj * 260 + pc + 4 * i) = v[i];
    }
    __syncthreads();
    {
        const int d = t;                        // 0..255
        const int tile = r0 >> 5, jh = (r0 >> 4) & 1;
        short* dst = MtG + (size_t)tile * (32 * EMBED) + d * 32 + jh * 16;
        #pragma unroll
        for (int g2 = 0; g2 < 2; ++g2) {
            short8v w;
            #pragma unroll
            for (int e = 0; e < 8; ++e) w[e] = f2h(L[(g2 * 8 + e) * 260 + d]);
            *(short8v*)(dst + g2 * 8) = w;
        }
    }
}

// ---------- main split-j flash kernel: BJ=64, 2 barriers/tile ----------
__launch_bounds__(NT, 2)
__global__ void attn(const short* __restrict__ MhG, const short* __restrict__ MtG,
                     const float* __restrict__ Ng, const int* __restrict__ iseval_p,
                     float* __restrict__ O0out, short* __restrict__ Ofp,
                     float* __restrict__ MLm, float* __restrict__ MLl, int n)
{
    __shared__ __align__(16) char smem[LDS_SZ];

    const int t = threadIdx.x, lane = t & 63, wave = t >> 6;
    const int quad = lane >> 4, mn = lane & 15;
    // XCD swizzle: bid%8 -> XCD; 2 XCDs per split (R7 mapping).
    const int bid = blockIdx.x;
    const int s  = (bid & 7) >> 1;               // split 0..3
    const int qb = ((bid >> 3) << 1) | (bid & 1);// 0..127
    const int q0 = qb * BQ;
    const int jbase = s * (n >> 2);
    const int jb32 = jbase / 32;                 // MtG 32-j tile index base
    const int ntiles = (n >> 2) / BJ;            // 32
    const int iseval = *iseval_p;
    const int jt = wave & 1, kh = wave >> 1;     // QK roles: j-half, K-half
    const int dq = wave;                         // PV d-quarter
    const int sq = t >> 2, sh = t & 3;           // softmax: row, 16-j chunk

    // ---- Q fragments fp16 (A-layout): this wave's K-half, scaled log2e ----
    const float L2E = 1.4426950408889634f;
    half8 Qf[4][4];
    #pragma unroll
    for (int qi = 0; qi < 4; ++qi) {
        const float* np = Ng + (size_t)(q0 + qi * 16 + mn) * EMBED;
        #pragma unroll
        for (int kk = 0; kk < 4; ++kk) {
            const float* p = np + (kh * 4 + kk) * 32 + quad * 8;
            float4 a = *(const float4*)p, b = *(const float4*)(p + 4);
            half8 h;
            h[0]=(_Float16)(a.x*L2E); h[1]=(_Float16)(a.y*L2E);
            h[2]=(_Float16)(a.z*L2E); h[3]=(_Float16)(a.w*L2E);
            h[4]=(_Float16)(b.x*L2E); h[5]=(_Float16)(b.y*L2E);
            h[6]=(_Float16)(b.z*L2E); h[7]=(_Float16)(b.w*L2E);
            Qf[qi][kk] = h;
        }
    }

    f32x4 O[4][4];
    #pragma unroll
    for (int qi = 0; qi < 4; ++qi)
        #pragma unroll
        for (int dt = 0; dt < 4; ++dt) O[qi][dt] = (f32x4){0.f, 0.f, 0.f, 0.f};

    float m_reg = -1e30f, l_reg = 0.f;   // row sq state (4 identical sh-copies)

    // QK B base: row j = jbase + tile*64 + jt*32 + jtt*16 + mn,
    // cols kh*128 + kk*32 + quad*8
    const short* mhb0 = MhG + (size_t)(jbase + jt * 32 + mn) * EMBED + kh * 128 + quad * 8;
    half8 Bc[2][4], Mtf[2][4];
    #pragma unroll
    for (int jtt = 0; jtt < 2; ++jtt)
        #pragma unroll
        for (int kk = 0; kk < 4; ++kk)
            Bc[jtt][kk] = *(const half8*)(mhb0 + (size_t)jtt * 16 * EMBED + kk * 32);

    for (int tt = 0; tt < ntiles; ++tt) {
        // --- Mt prefetch for this tile's PV (2 chunks), used post-b2 ---
        #pragma unroll
        for (int c = 0; c < 2; ++c) {
            const short* mtb = MtG + (size_t)(jb32 + 2 * tt + c) * (32 * EMBED);
            #pragma unroll
            for (int dt = 0; dt < 4; ++dt)
                Mtf[c][dt] = *(const half8*)(mtb + (dq * 64 + dt * 16 + mn) * 32 + quad * 8);
        }

        // --- QK^T: 4 q-tiles x 2 j-tiles x this wave's K-half -> SS plane kh ---
        {
            f32x4 a[4][2];
            #pragma unroll
            for (int qi = 0; qi < 4; ++qi)
                #pragma unroll
                for (int jtt = 0; jtt < 2; ++jtt) a[qi][jtt] = (f32x4){0,0,0,0};
            #pragma unroll
            for (int kk = 0; kk < 4; ++kk) {
                #pragma unroll
                for (int jtt = 0; jtt < 2; ++jtt) {
                    half8 bf = Bc[jtt][kk];
                    a[0][jtt] = mfma16(Qf[0][kk], bf, a[0][jtt]);
                    a[1][jtt] = mfma16(Qf[1][kk], bf, a[1][jtt]);
                    a[2][jtt] = mfma16(Qf[2][kk], bf, a[2][jtt]);
                    a[3][jtt] = mfma16(Qf[3][kk], bf, a[3][jtt]);
                }
            }
            float* ssp = (float*)(smem + SS_OFF) + kh * SS_PLW;
            #pragma unroll
            for (int qi = 0; qi < 4; ++qi)
                #pragma unroll
                for (int jtt = 0; jtt < 2; ++jtt)
                    #pragma unroll
                    for (int r = 0; r < 4; ++r)
                        ssp[(qi * 16 + quad * 4 + r) * 68 + jt * 32 + jtt * 16 + mn] = a[qi][jtt][r];
        }

        // --- Bc prefetch for tt+1 (in-place; latency spans b1+softmax+b2) ---
        if (tt + 1 < ntiles) {
            const short* nb = mhb0 + (size_t)(tt + 1) * (BJ * EMBED);
            #pragma unroll
            for (int jtt = 0; jtt < 2; ++jtt)
                #pragma unroll
                for (int kk = 0; kk < 4; ++kk)
                    Bc[jtt][kk] = *(const half8*)(nb + (size_t)jtt * 16 * EMBED + kk * 32);
        }

        __syncthreads();   // b1: SS visible

        // --- online softmax: thread (sq, sh) owns j = 16sh..16sh+15 ---
        {
            const int j0g = jbase + tt * BJ;
            const float* p0 = (const float*)(smem + SS_OFF) + sq * 68 + 16 * sh;
            float sv[16];
            #pragma unroll
            for (int g = 0; g < 4; ++g) {
                float4 x = *(const float4*)(p0 + 4 * g);
                float4 y = *(const float4*)(p0 + SS_PLW + 4 * g);
                sv[4*g+0] = x.x + y.x; sv[4*g+1] = x.y + y.y;
                sv[4*g+2] = x.z + y.z; sv[4*g+3] = x.w + y.w;
            }
            const int qg = q0 + sq;
            if (iseval) {
                if (qg == 0) {
                    #pragma unroll
                    for (int i = 0; i < 16; ++i) sv[i] = 0.f;
                }
            } else {
                int dj = qg - j0g - 16 * sh;
                #pragma unroll
                for (int i = 0; i < 16; ++i) if (dj == i) sv[i] = 0.f;
            }
            float mx = sv[0];
            #pragma unroll
            for (int i = 1; i < 16; ++i) mx = fmaxf(mx, sv[i]);
            mx = fmaxf(mx, __shfl_xor(mx, 1));
            mx = fmaxf(mx, __shfl_xor(mx, 2));
            float m_new = fmaxf(m_reg, mx);
            float alpha = exp2f(m_reg - m_new);
            float p[16], ps = 0.f;
            #pragma unroll
            for (int i = 0; i < 16; ++i) { p[i] = exp2f(sv[i] - m_new); ps += p[i]; }
            ps += __shfl_xor(ps, 1);
            ps += __shfl_xor(ps, 2);
            m_reg = m_new;
            l_reg = l_reg * alpha + ps;          // identical in all 4 sh-copies
            if (sh == 0)
                ((float*)(smem + AS_OFF))[sq] = alpha;
            char* pb = smem + PH_OFF + sq * 144 + sh * 32;
            #pragma unroll
            for (int g = 0; g < 2; ++g) {
                half8 ph;
                #pragma unroll
                for (int i = 0; i < 8; ++i) ph[i] = (_Float16)p[8 * g + i];
                *(half8*)(pb + 16 * g) = ph;
            }
        }

        __syncthreads();   // b2: PH/AS visible

        // --- PV: 4 q-tiles x this wave's 4 d-tiles, K=64 (2 chunks) ---
        #pragma unroll
        for (int qi = 0; qi < 4; ++qi) {
            const char* pr = smem + PH_OFF + (qi * 16 + mn) * 144 + quad * 16;
            half8 pf0 = *(const half8*)pr;          // j = quad*8..+7
            half8 pf1 = *(const half8*)(pr + 64);   // j = 32+quad*8..+7
            f32x4 al = *(const f32x4*)((const float*)(smem + AS_OFF) + qi * 16 + quad * 4);
            #pragma unroll
            for (int dt = 0; dt < 4; ++dt) {
                f32x4 o = O[qi][dt];
                o[0] *= al[0]; o[1] *= al[1]; o[2] *= al[2]; o[3] *= al[3];
                o = mfma16(pf0, Mtf[0][dt], o);
                O[qi][dt] = mfma16(pf1, Mtf[1][dt], o);
            }
        }
        // Hazards (2-barrier): SS rewrite (QK tt+1) after b2(tt) > softmax(tt)
        // read (pre-b2). PH/AS rewrite (softmax tt+1) after b1(tt+1) > PV(tt).
    }

    // ---- epilogue: partial O + (m,l) per split ----
    if (s == 0) {
        #pragma unroll
        for (int qi = 0; qi < 4; ++qi)
            #pragma unroll
            for (int dt = 0; dt < 4; ++dt) {
                int col = dq * 64 + dt * 16 + mn;
                #pragma unroll
                for (int r = 0; r < 4; ++r)
                    O0out[(size_t)(q0 + qi * 16 + quad * 4 + r) * EMBED + col] = O[qi][dt][r];
            }
    } else {
        short* dst = Ofp + (size_t)(s - 1) * n * EMBED;
        #pragma unroll
        for (int qi = 0; qi < 4; ++qi)
            #pragma unroll
            for (int dt = 0; dt < 4; ++dt) {
                int col = dq * 64 + dt * 16 + mn;
                #pragma unroll
                for (int r = 0; r < 4; ++r)
                    dst[(size_t)(q0 + qi * 16 + quad * 4 + r) * EMBED + col] = f2h(O[qi][dt][r]);
            }
    }
    if (sh == 0) {                     // one writer per q-row (sq = 0..63)
        MLm[s * n + q0 + sq] = m_reg;  // log2 domain
        MLl[s * n + q0 + sq] = l_reg;
    }
}

// ---------- combine 4 partials + gate + blend (m in log2 domain) ----------
__global__ void combine4(const float* __restrict__ O0, const short* __restrict__ Ofp,
                         const float* __restrict__ MLm, const float* __restrict__ MLl,
                         const float* __restrict__ Ng, const float* __restrict__ Wg,
                         const float* __restrict__ bg, const float* __restrict__ gb,
                         float* __restrict__ out, int n)
{
    const int t = threadIdx.x;
    const int row = blockIdx.x * 16 + (t >> 4);
    const int c = t & 15;
    float ms[4], ls[4];
    #pragma unroll
    for (int k = 0; k < 4; ++k) { ms[k] = MLm[k * n + row]; ls[k] = MLl[k * n + row]; }
    float m = fmaxf(fmaxf(ms[0], ms[1]), fmaxf(ms[2], ms[3]));
    float w[4], lsum = 0.f;
    #pragma unroll
    for (int k = 0; k < 4; ++k) { w[k] = exp2f(ms[k] - m); lsum += w[k] * ls[k]; }
    float linv = 1.f / lsum;

    float acc[16];
    {
        const float4* o0 = (const float4*)(O0 + (size_t)row * EMBED + c * 16);
        #pragma unroll
        for (int i = 0; i < 4; ++i) {
            float4 v = o0[i];
            acc[4*i+0] = w[0] * v.x; acc[4*i+1] = w[0] * v.y;
            acc[4*i+2] = w[0] * v.z; acc[4*i+3] = w[0] * v.w;
        }
    }
    #pragma unroll
    for (int k = 1; k < 4; ++k) {
        const short* op = Ofp + (size_t)(k - 1) * n * EMBED + (size_t)row * EMBED + c * 16;
        half8 a = *(const half8*)op, b = *(const half8*)(op + 8);
        #pragma unroll
        for (int i = 0; i < 8; ++i) {
            acc[i]     += w[k] * (float)a[i];
            acc[8 + i] += w[k] * (float)b[i];
        }
    }
    float dot = 0.f;
    #pragma unroll
    for (int i = 0; i < 16; ++i) { acc[i] *= linv; dot += acc[i] * Wg[c * 16 + i]; }
    dot += __shfl_xor(dot, 1);
    dot += __shfl_xor(dot, 2);
    dot += __shfl_xor(dot, 4);
    dot += __shfl_xor(dot, 8);
    float g = 1.f / (1.f + __expf(-(dot + bg[0] + gb[0])));
    const float4* n4 = (const float4*)(Ng + (size_t)row * EMBED + c * 16);
    float4* o4 = (float4*)(out + (size_t)row * EMBED + c * 16);
    #pragma unroll
    for (int i = 0; i < 4; ++i) {
        float4 nn = n4[i];
        float4 res;
        res.x = acc[4*i+0] * g + nn.x * (1.f - g);
        res.y = acc[4*i+1] * g + nn.y * (1.f - g);
        res.z = acc[4*i+2] * g + nn.z * (1.f - g);
        res.w = acc[4*i+3] * g + nn.w * (1.f - g);
        o4[i] = res;
    }
}

extern "C" void kernel_launch(void* const* d_in, const int* in_sizes, int n_in,
                              void* d_out, int out_size, void* d_ws, size_t ws_size,
                              hipStream_t stream) {
    const float* M      = (const float*)d_in[0];
    const float* N      = (const float*)d_in[1];
    const float* Wgp    = (const float*)d_in[2];
    const float* bgp    = (const float*)d_in[3];
    const float* gbp    = (const float*)d_in[4];
    const int*   iseval = (const int*)d_in[5];
    float* out = (float*)d_out;

    int n = in_sizes[0] / EMBED;   // 8192
    short* MhG = (short*)d_ws;                          // n*256 fp16 = 4 MB
    short* MtG = MhG + (size_t)n * EMBED;               // n*256 fp16 = 4 MB
    short* Ofp = MtG + (size_t)n * EMBED;               // 3*n*256 fp16 = 12 MB
    float* MLm = (float*)(Ofp + (size_t)3 * n * EMBED); // 4n f32
    float* MLl = MLm + 4 * n;                           // 4n f32
    // ws required ~20.3 MB

    hipLaunchKernelGGL(prep, dim3(n / 16), dim3(NT), 0, stream, M, MhG, MtG);
    hipLaunchKernelGGL(attn, dim3((n / BQ) * 4), dim3(NT), 0, stream,
                       MhG, MtG, N, iseval, out, Ofp, MLm, MLl, n);
    hipLaunchKernelGGL(combine4, dim3(n / 16), dim3(NT), 0, stream,
                       out, Ofp, MLm, MLl, N, Wgp, bgp, gbp, out, n);
}

// Round 15
// 184.971 us; speedup vs baseline: 1.0096x; 1.0096x over previous
//
#include <hip/hip_runtime.h>

// AttentionMatcher R19: R17 + counted-wait barrier (T3/T4 mechanism).
// R8-R18 post-mortem: attn is invariant at ~116us across tile size, barrier
// count, bank conflicts, softmax structure -> the constant is the
// __syncthreads() lowering: s_waitcnt vmcnt(0) lgkmcnt(0) + s_barrier
// (guide §5: the m97 ~20% stall). Every per-tile Bc/Mtf L2 prefetch gets
// force-drained at each barrier; no TLP can hide it (all waves wait).
// Fix: in-loop barrier = asm lgkmcnt(0) + raw s_barrier + sched_barrier(0).
// LDS ordering (SS/PH/AS) needs only lgkmcnt; global loads land in private
// regs and are waited at USE (compiler vmcnt(N)) -> prefetch truly spans
// the barrier. "memory" clobber + sched_barrier(0) pin LDS ops (m152/#18).
// out = gate * softmax(N M^T, diag<-0) M + (1-gate) * N,  n=8192, d=256, fp32.
//
// ws: MhG [n][256] fp16 row-major          (QK B-plane)
//     MtG [n/32 tiles][256 d][32 j] fp16   (PV B-plane, transposed tile-major)
//     Ofp 3 fp16 partial O planes (splits 1..3); split-0 partial f32 in d_out
//     MLm/MLl [4][n] f32 running max (log2 domain) / sum per split.

constexpr int EMBED = 256;
constexpr int BQ = 64;
constexpr int BJ = 32;
constexpr int NT = 256;

constexpr int SS_OFF = 0;            // 2 buf x 2 planes x (64 x 36) f32
constexpr int SS_BUF = 18432;        // bytes per SS buffer (2 planes)
constexpr int PH_OFF = 36864;        // 2 buf x 64 x 80 B
constexpr int PH_BUF = 5120;
constexpr int AS_OFF = 47104;        // 2 buf x 256 B
constexpr int AS_BUF = 256;
constexpr int LDS_SZ = 47616;        // x2 blocks/CU = 95.2 KB (<160)

typedef _Float16 half8 __attribute__((ext_vector_type(8)));
typedef float f32x4 __attribute__((ext_vector_type(4)));
typedef short short8v __attribute__((ext_vector_type(8)));

static __device__ __forceinline__ f32x4 mfma16(half8 a, half8 b, f32x4 c) {
    return __builtin_amdgcn_mfma_f32_16x16x32_f16(a, b, c, 0, 0, 0);
}
static __device__ __forceinline__ short f2h(float x) {
    return (short)__builtin_bit_cast(unsigned short, (_Float16)x);
}
// Barrier that orders LDS only: ds ops drained (lgkmcnt), global loads
// stay in flight (vmcnt NOT drained; compiler waits at use).
static __device__ __forceinline__ void barrier_lds() {
    asm volatile("s_waitcnt lgkmcnt(0)" ::: "memory");
    __builtin_amdgcn_s_barrier();
    __builtin_amdgcn_sched_barrier(0);
}

// ---------- prep: fp16 row plane + fp16 transposed tile plane ----------
__global__ void prep(const float* __restrict__ M,
                     short* __restrict__ MhG, short* __restrict__ MtG) {
    __shared__ float L[16 * 260];
    const int r0 = blockIdx.x * 16;            // 16 M-rows per block
    const int t = threadIdx.x;
    const int pj = t >> 4, pc = (t & 15) * 16;
    {
        const float* src = M + (size_t)(r0 + pj) * EMBED + pc;
        float4 v[4];
        #pragma unroll
        for (int i = 0; i < 4; ++i) v[i] = ((const float4*)src)[i];
        short* hd = MhG + (size_t)(r0 + pj) * EMBED + pc;
        #pragma unroll
        for (int i = 0; i < 2; ++i) {
            float4 a = v[2 * i], b = v[2 * i + 1];
            short8v h;
            h[0]=f2h(a.x); h[1]=f2h(a.y); h[2]=f2h(a.z); h[3]=f2h(a.w);
            h[4]=f2h(b.x); h[5]=f2h(b.y); h[6]=f2h(b.z); h[7]=f2h(b.w);
            *(short8v*)(hd + 8 * i) = h;
        }
        #pragma unroll
        for (int i = 0; i < 4; ++i)
            *(float4*)(L + pj * 260 + pc + 4 * i) = v[i];
    }
    __syncthreads();
    {
        const int d = t;                        // 0..255
        const int tile = r0 >> 5, jh = (r0 >> 4) & 1;
        short* dst = MtG + (size_t)tile * (BJ * EMBED) + d * BJ + jh * 16;
        #pragma unroll
        for (int g2 = 0; g2 < 2; ++g2) {
            short8v w;
            #pragma unroll
            for (int e = 0; e < 8; ++e) w[e] = f2h(L[(g2 * 8 + e) * 260 + d]);
            *(short8v*)(dst + g2 * 8) = w;
        }
    }
}

// ---------- main split-j flash kernel: 1-barrier pipelined (R12) ----------
__launch_bounds__(NT, 2)
__global__ void attn(const short* __restrict__ MhG, const short* __restrict__ MtG,
                     const float* __restrict__ Ng, const int* __restrict__ iseval_p,
                     float* __restrict__ O0out, short* __restrict__ Ofp,
                     float* __restrict__ MLm, float* __restrict__ MLl, int n)
{
    __shared__ __align__(16) char smem[LDS_SZ];

    const int t = threadIdx.x, lane = t & 63, wave = t >> 6;
    const int quad = lane >> 4, mn = lane & 15;
    // XCD swizzle: bid%8 -> XCD; 2 XCDs per split (R7 mapping).
    const int bid = blockIdx.x;
    const int s  = (bid & 7) >> 1;               // split 0..3
    const int qb = ((bid >> 3) << 1) | (bid & 1);// 0..127
    const int q0 = qb * BQ;
    const int jbase = s * (n >> 2);
    const int jb32 = jbase / BJ;
    const int ntiles = (n >> 2) / BJ;            // 64
    const int iseval = *iseval_p;
    const int jt = wave & 1, kh = wave >> 1;     // QK roles
    const int dq = wave;                         // PV d-quarter
    const int sq = t >> 2, sh = t & 3;           // softmax roles

    // ---- Q fragments fp16 (A-layout): this wave's K-half, scaled log2e ----
    const float L2E = 1.4426950408889634f;
    half8 Qf[4][4];
    #pragma unroll
    for (int qi = 0; qi < 4; ++qi) {
        const float* np = Ng + (size_t)(q0 + qi * 16 + mn) * EMBED;
        #pragma unroll
        for (int kk = 0; kk < 4; ++kk) {
            const float* p = np + (kh * 4 + kk) * 32 + quad * 8;
            float4 a = *(const float4*)p, b = *(const float4*)(p + 4);
            half8 h;
            h[0]=(_Float16)(a.x*L2E); h[1]=(_Float16)(a.y*L2E);
            h[2]=(_Float16)(a.z*L2E); h[3]=(_Float16)(a.w*L2E);
            h[4]=(_Float16)(b.x*L2E); h[5]=(_Float16)(b.y*L2E);
            h[6]=(_Float16)(b.z*L2E); h[7]=(_Float16)(b.w*L2E);
            Qf[qi][kk] = h;
        }
    }

    f32x4 O[4][4];
    #pragma unroll
    for (int qi = 0; qi < 4; ++qi)
        #pragma unroll
        for (int dt = 0; dt < 4; ++dt) O[qi][dt] = (f32x4){0.f, 0.f, 0.f, 0.f};

    float m_reg = -1e30f, l_reg = 0.f;   // row sq state (4 identical sh-copies)

    // QK B base: row j = jbase + tile*BJ + jt*16 + mn, cols kh*128 + kk*32 + quad*8
    const short* mhb0 = MhG + (size_t)(jbase + jt * 16 + mn) * EMBED + kh * 128 + quad * 8;
    half8 Bc[4], Bn[4], Mtf[4];
    #pragma unroll
    for (int kk = 0; kk < 4; ++kk) Bc[kk] = *(const half8*)(mhb0 + kk * 32);

    __syncthreads();

    // Pipelined loop: iter tt does QK(tt) || softmax(tt-1), barrier, PV(tt-1).
    for (int tt = 0; tt <= ntiles; ++tt) {
        const int bw = tt & 1;        // SS buffer written by QK(tt)
        const int br = bw ^ 1;        // buffer of tile tt-1 (valid for tt>0)

        // --- Mt prefetch for PV(tt-1): consumed after the barrier ---
        if (tt > 0) {
            const short* mtb = MtG + (size_t)(jb32 + (tt - 1)) * (BJ * EMBED);
            #pragma unroll
            for (int dt = 0; dt < 4; ++dt)
                Mtf[dt] = *(const half8*)(mtb + (dq * 64 + dt * 16 + mn) * BJ + quad * 8);
        }

        // --- QK^T(tt): 4 q-tiles x this wave's (jt, K-half) -> SS[bw] ---
        if (tt < ntiles) {
            f32x4 a0 = (f32x4){0,0,0,0}, a1 = (f32x4){0,0,0,0};
            f32x4 a2 = (f32x4){0,0,0,0}, a3 = (f32x4){0,0,0,0};
            #pragma unroll
            for (int kk = 0; kk < 4; ++kk) {
                half8 bf = Bc[kk];
                a0 = mfma16(Qf[0][kk], bf, a0);
                a1 = mfma16(Qf[1][kk], bf, a1);
                a2 = mfma16(Qf[2][kk], bf, a2);
                a3 = mfma16(Qf[3][kk], bf, a3);
            }
            float* ssp = (float*)(smem + SS_OFF + bw * SS_BUF) + kh * 2304;
            #pragma unroll
            for (int r = 0; r < 4; ++r) {
                ssp[(0  + quad * 4 + r) * 36 + jt * 16 + mn] = a0[r];
                ssp[(16 + quad * 4 + r) * 36 + jt * 16 + mn] = a1[r];
                ssp[(32 + quad * 4 + r) * 36 + jt * 16 + mn] = a2[r];
                ssp[(48 + quad * 4 + r) * 36 + jt * 16 + mn] = a3[r];
            }
        }

        // --- B-fragment prefetch for QK(tt+1): stays in flight across barrier ---
        if (tt + 1 < ntiles) {
            const short* nb = mhb0 + (size_t)(tt + 1) * (BJ * EMBED);
            #pragma unroll
            for (int kk = 0; kk < 4; ++kk) Bn[kk] = *(const half8*)(nb + kk * 32);
        }

        // --- online softmax(tt-1): thread (sq, sh) owns j = 8sh..8sh+7 ---
        if (tt > 0) {
            const int j0g = jbase + (tt - 1) * BJ;
            const float* p0 = (const float*)(smem + SS_OFF + br * SS_BUF) + sq * 36 + 8 * sh;
            float4 sa = *(const float4*)p0;
            float4 sb = *(const float4*)(p0 + 4);
            float4 sc = *(const float4*)(p0 + 2304);
            float4 sd = *(const float4*)(p0 + 2308);
            float sv[8] = {sa.x + sc.x, sa.y + sc.y, sa.z + sc.z, sa.w + sc.w,
                           sb.x + sd.x, sb.y + sd.y, sb.z + sd.z, sb.w + sd.w};
            const int qg = q0 + sq;
            if (iseval) {
                if (qg == 0) {
                    #pragma unroll
                    for (int i = 0; i < 8; ++i) sv[i] = 0.f;
                }
            } else {
                int dj = qg - j0g - 8 * sh;
                #pragma unroll
                for (int i = 0; i < 8; ++i) if (dj == i) sv[i] = 0.f;
            }
            float mx = sv[0];
            #pragma unroll
            for (int i = 1; i < 8; ++i) mx = fmaxf(mx, sv[i]);
            mx = fmaxf(mx, __shfl_xor(mx, 1));
            mx = fmaxf(mx, __shfl_xor(mx, 2));
            float m_new = fmaxf(m_reg, mx);
            float alpha = exp2f(m_reg - m_new);
            float p[8], ps = 0.f;
            #pragma unroll
            for (int i = 0; i < 8; ++i) { p[i] = exp2f(sv[i] - m_new); ps += p[i]; }
            ps += __shfl_xor(ps, 1);
            ps += __shfl_xor(ps, 2);
            m_reg = m_new;
            l_reg = l_reg * alpha + ps;          // identical in all 4 sh-copies
            if (sh == 0)
                ((float*)(smem + AS_OFF + br * AS_BUF))[sq] = alpha;
            half8 ph;
            #pragma unroll
            for (int i = 0; i < 8; ++i) ph[i] = (_Float16)p[i];
            *(half8*)(smem + PH_OFF + br * PH_BUF + sq * 80 + sh * 16) = ph;
        }

        barrier_lds();   // SS[bw] + PH/AS[br] visible; global loads NOT drained

        // --- PV(tt-1): 4 q-tiles x this wave's 4 d-tiles, K=32 ---
        if (tt > 0) {
            #pragma unroll
            for (int qi = 0; qi < 4; ++qi) {
                half8 pf = *(const half8*)(smem + PH_OFF + br * PH_BUF + (qi * 16 + mn) * 80 + quad * 16);
                f32x4 al = *(const f32x4*)((const float*)(smem + AS_OFF + br * AS_BUF) + qi * 16 + quad * 4);
                #pragma unroll
                for (int dt = 0; dt < 4; ++dt) {
                    f32x4 o = O[qi][dt];
                    o[0] *= al[0]; o[1] *= al[1]; o[2] *= al[2]; o[3] *= al[3];
                    O[qi][dt] = mfma16(pf, Mtf[dt], o);
                }
            }
        }

        #pragma unroll
        for (int kk = 0; kk < 4; ++kk) Bc[kk] = Bn[kk];
        // SS[bw] read by softmax(tt) in iter tt+1 BEFORE barrier(tt+1);
        // QK(tt+2) rewrites it after barrier(tt+1). Safe.
        // PH/AS[br] rewrite at softmax(tt+1) in iter tt+2, after barrier(tt+1)
        // which follows PV(tt-1). Safe.
    }

    // ---- epilogue: partial O + (m,l) per split ----
    if (s == 0) {
        #pragma unroll
        for (int qi = 0; qi < 4; ++qi)
            #pragma unroll
            for (int dt = 0; dt < 4; ++dt) {
                int col = dq * 64 + dt * 16 + mn;
                #pragma unroll
                for (int r = 0; r < 4; ++r)
                    O0out[(size_t)(q0 + qi * 16 + quad * 4 + r) * EMBED + col] = O[qi][dt][r];
            }
    } else {
        short* dst = Ofp + (size_t)(s - 1) * n * EMBED;
        #pragma unroll
        for (int qi = 0; qi < 4; ++qi)
            #pragma unroll
            for (int dt = 0; dt < 4; ++dt) {
                int col = dq * 64 + dt * 16 + mn;
                #pragma unroll
                for (int r = 0; r < 4; ++r)
                    dst[(size_t)(q0 + qi * 16 + quad * 4 + r) * EMBED + col] = f2h(O[qi][dt][r]);
            }
    }
    if (sh == 0) {                     // one writer per q-row (sq = 0..63)
        MLm[s * n + q0 + sq] = m_reg;  // log2 domain
        MLl[s * n + q0 + sq] = l_reg;
    }
}

// ---------- combine 4 partials + gate + blend (m in log2 domain) ----------
__global__ void combine4(const float* __restrict__ O0, const short* __restrict__ Ofp,
                         const float* __restrict__ MLm, const float* __restrict__ MLl,
                         const float* __restrict__ Ng, const float* __restrict__ Wg,
                         const float* __restrict__ bg, const float* __restrict__ gb,
                         float* __restrict__ out, int n)
{
    const int t = threadIdx.x;
    const int row = blockIdx.x * 16 + (t >> 4);
    const int c = t & 15;
    float ms[4], ls[4];
    #pragma unroll
    for (int k = 0; k < 4; ++k) { ms[k] = MLm[k * n + row]; ls[k] = MLl[k * n + row]; }
    float m = fmaxf(fmaxf(ms[0], ms[1]), fmaxf(ms[2], ms[3]));
    float w[4], lsum = 0.f;
    #pragma unroll
    for (int k = 0; k < 4; ++k) { w[k] = exp2f(ms[k] - m); lsum += w[k] * ls[k]; }
    float linv = 1.f / lsum;

    float acc[16];
    {
        const float4* o0 = (const float4*)(O0 + (size_t)row * EMBED + c * 16);
        #pragma unroll
        for (int i = 0; i < 4; ++i) {
            float4 v = o0[i];
            acc[4*i+0] = w[0] * v.x; acc[4*i+1] = w[0] * v.y;
            acc[4*i+2] = w[0] * v.z; acc[4*i+3] = w[0] * v.w;
        }
    }
    #pragma unroll
    for (int k = 1; k < 4; ++k) {
        const short* op = Ofp + (size_t)(k - 1) * n * EMBED + (size_t)row * EMBED + c * 16;
        half8 a = *(const half8*)op, b = *(const half8*)(op + 8);
        #pragma unroll
        for (int i = 0; i < 8; ++i) {
            acc[i]     += w[k] * (float)a[i];
            acc[8 + i] += w[k] * (float)b[i];
        }
    }
    float dot = 0.f;
    #pragma unroll
    for (int i = 0; i < 16; ++i) { acc[i] *= linv; dot += acc[i] * Wg[c * 16 + i]; }
    dot += __shfl_xor(dot, 1);
    dot += __shfl_xor(dot, 2);
    dot += __shfl_xor(dot, 4);
    dot += __shfl_xor(dot, 8);
    float g = 1.f / (1.f + __expf(-(dot + bg[0] + gb[0])));
    const float4* n4 = (const float4*)(Ng + (size_t)row * EMBED + c * 16);
    float4* o4 = (float4*)(out + (size_t)row * EMBED + c * 16);
    #pragma unroll
    for (int i = 0; i < 4; ++i) {
        float4 nn = n4[i];
        float4 res;
        res.x = acc[4*i+0] * g + nn.x * (1.f - g);
        res.y = acc[4*i+1] * g + nn.y * (1.f - g);
        res.z = acc[4*i+2] * g + nn.z * (1.f - g);
        res.w = acc[4*i+3] * g + nn.w * (1.f - g);
        o4[i] = res;
    }
}

extern "C" void kernel_launch(void* const* d_in, const int* in_sizes, int n_in,
                              void* d_out, int out_size, void* d_ws, size_t ws_size,
                              hipStream_t stream) {
    const float* M      = (const float*)d_in[0];
    const float* N      = (const float*)d_in[1];
    const float* Wgp    = (const float*)d_in[2];
    const float* bgp    = (const float*)d_in[3];
    const float* gbp    = (const float*)d_in[4];
    const int*   iseval = (const int*)d_in[5];
    float* out = (float*)d_out;

    int n = in_sizes[0] / EMBED;   // 8192
    short* MhG = (short*)d_ws;                          // n*256 fp16 = 4 MB
    short* MtG = MhG + (size_t)n * EMBED;               // n*256 fp16 = 4 MB
    short* Ofp = MtG + (size_t)n * EMBED;               // 3*n*256 fp16 = 12 MB
    float* MLm = (float*)(Ofp + (size_t)3 * n * EMBED); // 4n f32
    float* MLl = MLm + 4 * n;                           // 4n f32
    // ws required ~20.3 MB

    hipLaunchKernelGGL(prep, dim3(n / 16), dim3(NT), 0, stream, M, MhG, MtG);
    hipLaunchKernelGGL(attn, dim3((n / BQ) * 4), dim3(NT), 0, stream,
                       MhG, MtG, N, iseval, out, Ofp, MLm, MLl, n);
    hipLaunchKernelGGL(combine4, dim3(n / 16), dim3(NT), 0, stream,
                       out, Ofp, MLm, MLl, N, Wgp, bgp, gbp, out, n);
}